// Round 10
// baseline (287.440 us; speedup 1.0000x reference)
//
#include <hip/hip_runtime.h>
#include <hip/hip_bf16.h>
#include <math.h>

#define BATCH   2
#define SEQLEN  1024
#define DMODEL  1024
#define DINNER  2048
#define DSTATE  16
#define DTRANK  64
#define XPAD    128             // padded x_dbl partial row stride (96 -> 128)
#define MROWS   (BATCH*SEQLEN)  // 2048
#define NSEG2   32              // serial-n scan segments
#define SEGL2   (SEQLEN/NSEG2)  // 32 rows per segment
#define XP_SPLIT  8

typedef float    f32x4  __attribute__((ext_vector_type(4)));
typedef _Float16 f16x8  __attribute__((ext_vector_type(8)));
typedef _Float16 f16x4  __attribute__((ext_vector_type(4)));

// convert 8 consecutive f32 -> f16x8 (same rounding as the old f2h kernel)
__device__ __forceinline__ f16x8 cvt_f32x8(const float* p) {
  float4 a = *(const float4*)p;
  float4 b = *(const float4*)(p + 4);
  f16x8 r;
  r[0] = (_Float16)a.x; r[1] = (_Float16)a.y;
  r[2] = (_Float16)a.z; r[3] = (_Float16)a.w;
  r[4] = (_Float16)b.x; r[5] = (_Float16)b.y;
  r[6] = (_Float16)b.z; r[7] = (_Float16)b.w;
  return r;
}

// ---------------------------------------------------------------------------
// Pipelined MFMA GEMM, 128x128 tile, BK=64, 4 waves 2x2. A,W are fp32 in
// global (converted to f16 during staging). EPI 4: f16 store (in_proj).
// ---------------------------------------------------------------------------
__global__ __launch_bounds__(256) void pgemm128_f32(
    const float* __restrict__ A, int lda,
    const float* __restrict__ W, int ldw,
    _Float16* __restrict__ C16, int ldc, int K)
{
  constexpr int PS = 1032;            // plane stride halves: 128*8 + 8 pad
  __shared__ _Float16 As[2][8 * PS];  // 16.5 KB each
  __shared__ _Float16 Bs[2][8 * PS];

  const int t  = threadIdx.x;
  const int m0 = blockIdx.y * 128, n0 = blockIdx.x * 128;
  const int nIter = K / 64;

  const int kb = t & 7;
  const int r0 = t >> 3;
  const float* gA = A + (size_t)(m0 + r0) * lda + kb * 8;
  const float* gB = W + (size_t)(n0 + r0) * ldw + kb * 8;
  const size_t a32 = (size_t)32 * lda;
  const size_t b32 = (size_t)32 * ldw;
  const int soff = kb * PS + r0 * 8;

  {
    f16x8 ar[4], br[4];
#pragma unroll
    for (int j = 0; j < 4; ++j) {
      ar[j] = cvt_f32x8(gA + j * a32);
      br[j] = cvt_f32x8(gB + j * b32);
    }
    gA += 64; gB += 64;
#pragma unroll
    for (int j = 0; j < 4; ++j) {
      *(f16x8*)&As[0][soff + j * 256] = ar[j];
      *(f16x8*)&Bs[0][soff + j * 256] = br[j];
    }
  }

  const int lane = t & 63, wvi = t >> 6;
  const int wm = (wvi >> 1) * 64, wn = (wvi & 1) * 64;
  const int lm = lane & 15, lk = lane >> 4;

  f32x4 acc[4][4] = {};

  for (int it = 0; it < nIter; ++it) {
    __syncthreads();
    const bool more = (it + 1 < nIter);
    f16x8 ar[4], br[4];
    if (more) {
#pragma unroll
      for (int j = 0; j < 4; ++j) {
        ar[j] = cvt_f32x8(gA + j * a32);
        br[j] = cvt_f32x8(gB + j * b32);
      }
      gA += 64; gB += 64;
    }
    const int cb = it & 1;
#pragma unroll
    for (int s = 0; s < 2; ++s) {
      f16x8 av[4], bv[4];
#pragma unroll
      for (int i = 0; i < 4; ++i)
        av[i] = *(const f16x8*)&As[cb][(s * 4 + lk) * PS + (wm + i * 16 + lm) * 8];
#pragma unroll
      for (int j = 0; j < 4; ++j)
        bv[j] = *(const f16x8*)&Bs[cb][(s * 4 + lk) * PS + (wn + j * 16 + lm) * 8];
#pragma unroll
      for (int i = 0; i < 4; ++i)
#pragma unroll
        for (int j = 0; j < 4; ++j)
          acc[i][j] = __builtin_amdgcn_mfma_f32_16x16x32_f16(av[i], bv[j], acc[i][j], 0, 0, 0);
    }
    if (more) {
      const int nb = (it + 1) & 1;
#pragma unroll
      for (int j = 0; j < 4; ++j) {
        *(f16x8*)&As[nb][soff + j * 256] = ar[j];
        *(f16x8*)&Bs[nb][soff + j * 256] = br[j];
      }
    }
  }

#pragma unroll
  for (int i = 0; i < 4; ++i) {
    const int mrow = m0 + wm + i * 16 + lk * 4;
#pragma unroll
    for (int j = 0; j < 4; ++j) {
      const int col = n0 + wn + j * 16 + lm;
#pragma unroll
      for (int r = 0; r < 4; ++r)
        C16[(size_t)(mrow + r) * ldc + col] = (_Float16)acc[i][j][r];
    }
  }
}

// ---------------------------------------------------------------------------
// Pipelined MFMA GEMM, 64x128 tile, BK=64.  A is f16; W is fp32 in global
// (converted during staging; rows >= WROWS read as zero).  fp32 C store,
// split-K via gridDim.z (+zstride).  Used for x_proj (WROWS=96) and
// out_proj (WROWS=1024, gridDim.z=1, direct store).
// ---------------------------------------------------------------------------
template<int WROWS>
__global__ __launch_bounds__(256) void pgemm64f(
    const _Float16* __restrict__ A, int lda,
    const float* __restrict__ Wf, int ldw,
    float* __restrict__ C, int ldc, int K, size_t zstride)
{
  constexpr int APS = 520;    // A kb-plane stride (halves): 64*8 + 8 pad
  constexpr int BPS = 1032;   // B kb-plane stride: 128*8 + 8 pad
  __shared__ _Float16 As[2][8 * APS];
  __shared__ _Float16 Bs[2][8 * BPS];

  const int t  = threadIdx.x;
  const int m0 = blockIdx.y * 64, n0 = blockIdx.x * 128;
  const int kchunk = K / gridDim.z;
  const int kbeg = blockIdx.z * kchunk;
  const int nIter = kchunk / 64;

  const int kb = t & 7;
  const int r0 = t >> 3;
  const _Float16* gA = A + (size_t)(m0 + r0) * lda + kbeg + kb * 8;
  const float*    gB = Wf + (size_t)(n0 + r0) * ldw + kbeg + kb * 8;
  const size_t a32 = (size_t)32 * lda;
  const size_t b32 = (size_t)32 * ldw;
  const int aoff = kb * APS + r0 * 8;
  const int boff = kb * BPS + r0 * 8;

  {
    f16x8 a0 = *(const f16x8*)(gA);
    f16x8 a1 = *(const f16x8*)(gA + a32);
    f16x8 br[4];
#pragma unroll
    for (int j = 0; j < 4; ++j) {
      if (n0 + r0 + 32 * j < WROWS) br[j] = cvt_f32x8(gB + j * b32);
      else                          br[j] = (f16x8){};
    }
    gA += 64; gB += 64;
    *(f16x8*)&As[0][aoff]       = a0;
    *(f16x8*)&As[0][aoff + 256] = a1;
#pragma unroll
    for (int j = 0; j < 4; ++j)
      *(f16x8*)&Bs[0][boff + j * 256] = br[j];
  }

  const int lane = t & 63, wvi = t >> 6;
  const int wn = wvi * 32;
  const int lm = lane & 15, lk = lane >> 4;

  f32x4 acc[4][2] = {};

  for (int it = 0; it < nIter; ++it) {
    __syncthreads();
    const bool more = (it + 1 < nIter);
    f16x8 a0, a1, br[4];
    if (more) {
      a0 = *(const f16x8*)(gA);
      a1 = *(const f16x8*)(gA + a32);
#pragma unroll
      for (int j = 0; j < 4; ++j) {
        if (n0 + r0 + 32 * j < WROWS) br[j] = cvt_f32x8(gB + j * b32);
        else                          br[j] = (f16x8){};
      }
      gA += 64; gB += 64;
    }
    const int cb = it & 1;
#pragma unroll
    for (int s = 0; s < 2; ++s) {
      f16x8 av[4], bv[2];
#pragma unroll
      for (int i = 0; i < 4; ++i)
        av[i] = *(const f16x8*)&As[cb][(s * 4 + lk) * APS + (i * 16 + lm) * 8];
#pragma unroll
      for (int j = 0; j < 2; ++j)
        bv[j] = *(const f16x8*)&Bs[cb][(s * 4 + lk) * BPS + (wn + j * 16 + lm) * 8];
#pragma unroll
      for (int i = 0; i < 4; ++i)
#pragma unroll
        for (int j = 0; j < 2; ++j)
          acc[i][j] = __builtin_amdgcn_mfma_f32_16x16x32_f16(av[i], bv[j], acc[i][j], 0, 0, 0);
    }
    if (more) {
      const int nb = (it + 1) & 1;
      *(f16x8*)&As[nb][aoff]       = a0;
      *(f16x8*)&As[nb][aoff + 256] = a1;
#pragma unroll
      for (int j = 0; j < 4; ++j)
        *(f16x8*)&Bs[nb][boff + j * 256] = br[j];
    }
  }

  float* Cz = C + (size_t)blockIdx.z * zstride;
#pragma unroll
  for (int i = 0; i < 4; ++i) {
    const int mrow = m0 + i * 16 + lk * 4;
#pragma unroll
    for (int j = 0; j < 2; ++j) {
      const int col = n0 + wn + j * 16 + lm;
#pragma unroll
      for (int r = 0; r < 4; ++r)
        Cz[(size_t)(mrow + r) * ldc + col] = acc[i][j][r];
    }
  }
}

// ---------------------------------------------------------------------------
// Causal depthwise conv (k=4) + bias + SiLU; xz is f16; writes u16.
// ---------------------------------------------------------------------------
__global__ __launch_bounds__(256) void conv_silu(
    const _Float16* __restrict__ xz16,
    const float* __restrict__ conv_w,
    const float* __restrict__ conv_b,
    _Float16* __restrict__ u16)
{
  const int idx = blockIdx.x * 256 + threadIdx.x;  // row*DINNER + d
  const int d   = idx & (DINNER - 1);
  const int row = idx >> 11;
  const int l   = row & (SEQLEN - 1);
  float s = conv_b[d];
#pragma unroll
  for (int k = 0; k < 4; ++k) {
    int lt = l + k - 3;
    if (lt >= 0)
      s = fmaf((float)xz16[(size_t)(row + k - 3) * (2 * DINNER) + d],
               conv_w[d * 4 + k], s);
  }
  float v = s / (1.f + __expf(-s));
  u16[idx] = (_Float16)v;
}

// ---------------------------------------------------------------------------
// sum the XP_SPLIT x_proj partials inline (same order as old reduce_xdbl)
// ---------------------------------------------------------------------------
__device__ __forceinline__ f32x4 red8(const float* __restrict__ part, size_t idx) {
  f32x4 s = *(const f32x4*)(part + idx);
#pragma unroll
  for (int z = 1; z < XP_SPLIT; ++z)
    s += *(const f32x4*)(part + (size_t)z * (MROWS * XPAD) + idx);
  return s;
}

// ---------------------------------------------------------------------------
// Serial-n selective scan with fused dt-projection (R9 structure), now
// reading the x_proj partials directly (inline split-K reduction).
// Pass A (scan_pe):  delta = softplus(xdbl.w + 2b) -> delta16; per-segment
//                    P_n = exp(A_dn*sum(delta)), E_n (carry=0)
// Pass B (scan_mid): chain segments -> carry-in states per (d,b,seg,n)
// Pass C (scan_y):   rescan with carry + y = sum_n s_n*C_n, D-skip, gate.
// ---------------------------------------------------------------------------
__global__ __launch_bounds__(256) void scan_pe(
    const _Float16* __restrict__ u16,
    const float* __restrict__ part,        // [XP_SPLIT][MROWS][XPAD]
    const float* __restrict__ A_log,
    const float* __restrict__ dt_w,        // fp32 [DINNER][DTRANK]
    const float* __restrict__ dt_b,        // fp32 [DINNER]
    float* __restrict__ pbuf, float* __restrict__ ebuf,
    _Float16* __restrict__ delta16)
{
  const int t = threadIdx.x;
  const int d = blockIdx.x * 256 + t;
  const int b   = blockIdx.y >> 5;        // NSEG2 = 32
  const int seg = blockIdx.y & 31;
  const int row0 = b * SEQLEN + seg * SEGL2;

  f32x4 w[16];
#pragma unroll
  for (int q = 0; q < 16; ++q)
    w[q] = *(const f32x4*)&dt_w[(size_t)d * DTRANK + q * 4];
  const float b2 = 2.f * dt_b[d];

  float A_dn[DSTATE];
#pragma unroll
  for (int q = 0; q < 4; ++q) {
    f32x4 a4 = *(const f32x4*)&A_log[(size_t)d * DSTATE + q * 4];
#pragma unroll
    for (int e = 0; e < 4; ++e) A_dn[q * 4 + e] = -__expf(a4[e]);
  }

  __shared__ __align__(16) float xd[SEGL2 * 64];       // 8 KB, broadcast reads
  __shared__ __align__(16) float Bl[SEGL2 * DSTATE];   // 2 KB
  {
#pragma unroll
    for (int k = 0; k < 2; ++k) {
      int idx = t * 2 + k;
      int i = idx >> 4, c4 = (idx & 15) * 4;
      *(f32x4*)&xd[i * 64 + c4] = red8(part, (size_t)(row0 + i) * XPAD + c4);
    }
    if (t < 128) {
      int i = t >> 2, n4 = (t & 3) * 4;
      *(f32x4*)&Bl[i * DSTATE + n4] =
          red8(part, (size_t)(row0 + i) * XPAD + DTRANK + n4);
    }
  }
  __syncthreads();

  float E[DSTATE];
#pragma unroll
  for (int n = 0; n < DSTATE; ++n) E[n] = 0.f;
  float S = 0.f;

  for (int i = 0; i < SEGL2; ++i) {
    float a = b2;
#pragma unroll
    for (int q = 0; q < 16; ++q) {
      f32x4 x4 = *(const f32x4*)&xd[i * 64 + q * 4];
      a = fmaf(x4[0], w[q][0], a);
      a = fmaf(x4[1], w[q][1], a);
      a = fmaf(x4[2], w[q][2], a);
      a = fmaf(x4[3], w[q][3], a);
    }
    float dv = (a > 20.f) ? a : __logf(1.f + __expf(a));
    const size_t ro = (size_t)(row0 + i) * DINNER + d;
    delta16[ro] = (_Float16)dv;
    dv = (float)(_Float16)dv;              // match scan_y's f16-rounded delta
    float uv = (float)u16[ro];
    float du = dv * uv;
    S += dv;
#pragma unroll
    for (int n = 0; n < DSTATE; ++n) {
      float dA = __expf(dv * A_dn[n]);
      E[n] = fmaf(dA, E[n], du * Bl[i * DSTATE + n]);
    }
  }

  const size_t base = ((size_t)(b * NSEG2 + seg) * DSTATE) * DINNER + d;
#pragma unroll
  for (int n = 0; n < DSTATE; ++n) {
    pbuf[base + (size_t)n * DINNER] = __expf(S * A_dn[n]);
    ebuf[base + (size_t)n * DINNER] = E[n];
  }
}

__global__ __launch_bounds__(256) void scan_mid(
    const float* __restrict__ pbuf, const float* __restrict__ ebuf,
    float* __restrict__ cbuf)
{
  // idx over (b, n, d): 2*16*2048 = 65536 threads
  const int idx = blockIdx.x * 256 + threadIdx.x;
  const int d = idx & (DINNER - 1);
  const int n = (idx >> 11) & 15;
  const int b = idx >> 15;
  float s = 0.f;
  for (int seg = 0; seg < NSEG2; ++seg) {
    const size_t off = ((size_t)(b * NSEG2 + seg) * DSTATE + n) * DINNER + d;
    cbuf[off] = s;
    s = fmaf(pbuf[off], s, ebuf[off]);
  }
}

__global__ __launch_bounds__(256) void scan_y(
    const _Float16* __restrict__ delta16,
    const _Float16* __restrict__ u16,
    const _Float16* __restrict__ xz16,     // z = xz16[:, DINNER:]
    const float* __restrict__ part,        // x_proj partials
    const float* __restrict__ A_log,
    const float* __restrict__ Dp,
    const float* __restrict__ cbuf,
    _Float16* __restrict__ y16)
{
  const int t = threadIdx.x;
  const int d = blockIdx.x * 256 + t;
  const int b   = blockIdx.y >> 5;
  const int seg = blockIdx.y & 31;
  const int row0 = b * SEQLEN + seg * SEGL2;

  float A_dn[DSTATE];
#pragma unroll
  for (int q = 0; q < 4; ++q) {
    f32x4 a4 = *(const f32x4*)&A_log[(size_t)d * DSTATE + q * 4];
#pragma unroll
    for (int e = 0; e < 4; ++e) A_dn[q * 4 + e] = -__expf(a4[e]);
  }
  const float Dv = Dp[d];

  __shared__ __align__(16) float Bl[SEGL2 * DSTATE];   // 2 KB each
  __shared__ __align__(16) float Cl[SEGL2 * DSTATE];
  if (t < 128) {
    int i = t >> 2, n4 = (t & 3) * 4;
    *(f32x4*)&Bl[i * DSTATE + n4] =
        red8(part, (size_t)(row0 + i) * XPAD + DTRANK + n4);
  } else {
    int u = t - 128;
    int i = u >> 2, n4 = (u & 3) * 4;
    *(f32x4*)&Cl[i * DSTATE + n4] =
        red8(part, (size_t)(row0 + i) * XPAD + DTRANK + DSTATE + n4);
  }
  __syncthreads();

  float s[DSTATE];
  {
    const size_t base = ((size_t)(b * NSEG2 + seg) * DSTATE) * DINNER + d;
#pragma unroll
    for (int n = 0; n < DSTATE; ++n) s[n] = cbuf[base + (size_t)n * DINNER];
  }

  for (int i = 0; i < SEGL2; ++i) {
    const size_t ro = (size_t)(row0 + i) * DINNER + d;
    float dv = (float)delta16[ro];
    float uv = (float)u16[ro];
    float zv = (float)xz16[(size_t)(row0 + i) * (2 * DINNER) + DINNER + d];
    float du = dv * uv;
    float y = 0.f;
#pragma unroll
    for (int n = 0; n < DSTATE; ++n) {
      float dA = __expf(dv * A_dn[n]);
      s[n] = fmaf(dA, s[n], du * Bl[i * DSTATE + n]);
      y = fmaf(s[n], Cl[i * DSTATE + n], y);
    }
    y = fmaf(uv, Dv, y);
    y *= zv / (1.f + __expf(-zv));
    y16[ro] = (_Float16)y;
  }
}

// ---------------------------------------------------------------------------
extern "C" void kernel_launch(void* const* d_in, const int* in_sizes, int n_in,
                              void* d_out, int out_size, void* d_ws, size_t ws_size,
                              hipStream_t stream)
{
  const float* hidden     = (const float*)d_in[0];
  const float* in_proj_w  = (const float*)d_in[1];
  const float* conv_w     = (const float*)d_in[2];
  const float* conv_b     = (const float*)d_in[3];
  const float* x_proj_w   = (const float*)d_in[4];
  const float* dt_proj_w  = (const float*)d_in[5];
  const float* dt_proj_b  = (const float*)d_in[6];
  const float* A_log      = (const float*)d_in[7];
  const float* Dp         = (const float*)d_in[8];
  const float* out_proj_w = (const float*)d_in[9];
  float* out = (float*)d_out;

  char* p = (char*)d_ws;
  _Float16* xz16    = (_Float16*)p;  p += (size_t)MROWS * 2 * DINNER * 2;  // 16.8MB
  _Float16* u16     = (_Float16*)p;  p += (size_t)MROWS * DINNER * 2;      // 8.4MB
  _Float16* delta16 = (_Float16*)p;  p += (size_t)MROWS * DINNER * 2;      // 8.4MB
  _Float16* y16     = (_Float16*)p;  p += (size_t)MROWS * DINNER * 2;      // 8.4MB
  float*    xp_part = (float*)p;     p += (size_t)XP_SPLIT * MROWS * XPAD * 4; // 8.4MB
  float*    pbuf    = (float*)p;     p += (size_t)BATCH * NSEG2 * DSTATE * DINNER * 4; // 8.4MB
  float*    ebuf    = (float*)p;     p += (size_t)BATCH * NSEG2 * DSTATE * DINNER * 4; // 8.4MB
  float*    cbuf    = (float*)p;     p += (size_t)BATCH * NSEG2 * DSTATE * DINNER * 4; // 8.4MB

  // 1. in_proj: xz16 = f16(hidden @ in_proj_w^T)  [2048, 4096], K=1024
  //    (f32 operands converted in staging -- f2h dispatch eliminated)
  pgemm128_f32<<<dim3(4096 / 128, MROWS / 128), 256, 0, stream>>>(
      hidden, DMODEL, in_proj_w, DMODEL, xz16, 4096, DMODEL);

  // 2. conv + SiLU -> u16
  conv_silu<<<(MROWS * DINNER) / 256, 256, 0, stream>>>(xz16, conv_w, conv_b, u16);

  // 3. x_proj: partials[z] = u @ x_proj_w^T chunk  [2048,128], split-K=8
  //    (W read from fp32 directly; rows 96..127 zero-padded in staging)
  pgemm64f<96><<<dim3(1, MROWS / 64, XP_SPLIT), 256, 0, stream>>>(
      u16, DINNER, x_proj_w, DINNER, xp_part, XPAD, DINNER,
      (size_t)MROWS * XPAD);

  // 4+5. serial-n scan, fused dt-projection, inline split-K reduction:
  //      (delta,P,E) -> carry chain -> y
  scan_pe<<<dim3(DINNER / 256, BATCH * NSEG2), 256, 0, stream>>>(
      u16, xp_part, A_log, dt_proj_w, dt_proj_b, pbuf, ebuf, delta16);
  scan_mid<<<(BATCH * DSTATE * DINNER) / 256, 256, 0, stream>>>(pbuf, ebuf, cbuf);
  scan_y<<<dim3(DINNER / 256, BATCH * NSEG2), 256, 0, stream>>>(
      delta16, u16, xz16, xp_part, A_log, Dp, cbuf, y16);

  // 6. out_proj: out = y @ out_proj_w^T  [2048,1024], K=2048, no split-K
  //    (direct fp32 store -- reduce_out dispatch eliminated)
  pgemm64f<DMODEL><<<dim3(DMODEL / 128, MROWS / 64, 1), 256, 0, stream>>>(
      y16, DINNER, out_proj_w, DINNER, out, DMODEL, DINNER, 0);
}

// Round 11
// 238.011 us; speedup vs baseline: 1.2077x; 1.2077x over previous
//
#include <hip/hip_runtime.h>
#include <hip/hip_bf16.h>
#include <math.h>

#define BATCH   2
#define SEQLEN  1024
#define DMODEL  1024
#define DINNER  2048
#define DSTATE  16
#define DTRANK  64
#define XPAD    128             // padded x_dbl partial row stride (96 -> 128)
#define MROWS   (BATCH*SEQLEN)  // 2048
#define NSEG2   32              // serial-n scan segments
#define SEGL2   (SEQLEN/NSEG2)  // 32 rows per segment
#define XP_SPLIT  8
#define OUT_SPLIT 4

typedef float    f32x4  __attribute__((ext_vector_type(4)));
typedef _Float16 f16x8  __attribute__((ext_vector_type(8)));
typedef _Float16 f16x4  __attribute__((ext_vector_type(4)));

// convert 8 consecutive f32 -> f16x8
__device__ __forceinline__ f16x8 cvt_f32x8(const float* p) {
  float4 a = *(const float4*)p;
  float4 b = *(const float4*)(p + 4);
  f16x8 r;
  r[0] = (_Float16)a.x; r[1] = (_Float16)a.y;
  r[2] = (_Float16)a.z; r[3] = (_Float16)a.w;
  r[4] = (_Float16)b.x; r[5] = (_Float16)b.y;
  r[6] = (_Float16)b.z; r[7] = (_Float16)b.w;
  return r;
}

// ---------------------------------------------------------------------------
// Pipelined MFMA GEMM, 128x128 tile, BK=64, 4 waves 2x2. A,W fp32 in global
// (converted to f16 during staging). f16 store (in_proj).
// ---------------------------------------------------------------------------
__global__ __launch_bounds__(256) void pgemm128_f32(
    const float* __restrict__ A, int lda,
    const float* __restrict__ W, int ldw,
    _Float16* __restrict__ C16, int ldc, int K)
{
  constexpr int PS = 1032;            // plane stride halves: 128*8 + 8 pad
  __shared__ _Float16 As[2][8 * PS];
  __shared__ _Float16 Bs[2][8 * PS];

  const int t  = threadIdx.x;
  const int m0 = blockIdx.y * 128, n0 = blockIdx.x * 128;
  const int nIter = K / 64;

  const int kb = t & 7;
  const int r0 = t >> 3;
  const float* gA = A + (size_t)(m0 + r0) * lda + kb * 8;
  const float* gB = W + (size_t)(n0 + r0) * ldw + kb * 8;
  const size_t a32 = (size_t)32 * lda;
  const size_t b32 = (size_t)32 * ldw;
  const int soff = kb * PS + r0 * 8;

  {
    f16x8 ar[4], br[4];
#pragma unroll
    for (int j = 0; j < 4; ++j) {
      ar[j] = cvt_f32x8(gA + j * a32);
      br[j] = cvt_f32x8(gB + j * b32);
    }
    gA += 64; gB += 64;
#pragma unroll
    for (int j = 0; j < 4; ++j) {
      *(f16x8*)&As[0][soff + j * 256] = ar[j];
      *(f16x8*)&Bs[0][soff + j * 256] = br[j];
    }
  }

  const int lane = t & 63, wvi = t >> 6;
  const int wm = (wvi >> 1) * 64, wn = (wvi & 1) * 64;
  const int lm = lane & 15, lk = lane >> 4;

  f32x4 acc[4][4] = {};

  for (int it = 0; it < nIter; ++it) {
    __syncthreads();
    const bool more = (it + 1 < nIter);
    f16x8 ar[4], br[4];
    if (more) {
#pragma unroll
      for (int j = 0; j < 4; ++j) {
        ar[j] = cvt_f32x8(gA + j * a32);
        br[j] = cvt_f32x8(gB + j * b32);
      }
      gA += 64; gB += 64;
    }
    const int cb = it & 1;
#pragma unroll
    for (int s = 0; s < 2; ++s) {
      f16x8 av[4], bv[4];
#pragma unroll
      for (int i = 0; i < 4; ++i)
        av[i] = *(const f16x8*)&As[cb][(s * 4 + lk) * PS + (wm + i * 16 + lm) * 8];
#pragma unroll
      for (int j = 0; j < 4; ++j)
        bv[j] = *(const f16x8*)&Bs[cb][(s * 4 + lk) * PS + (wn + j * 16 + lm) * 8];
#pragma unroll
      for (int i = 0; i < 4; ++i)
#pragma unroll
        for (int j = 0; j < 4; ++j)
          acc[i][j] = __builtin_amdgcn_mfma_f32_16x16x32_f16(av[i], bv[j], acc[i][j], 0, 0, 0);
    }
    if (more) {
      const int nb = (it + 1) & 1;
#pragma unroll
      for (int j = 0; j < 4; ++j) {
        *(f16x8*)&As[nb][soff + j * 256] = ar[j];
        *(f16x8*)&Bs[nb][soff + j * 256] = br[j];
      }
    }
  }

#pragma unroll
  for (int i = 0; i < 4; ++i) {
    const int mrow = m0 + wm + i * 16 + lk * 4;
#pragma unroll
    for (int j = 0; j < 4; ++j) {
      const int col = n0 + wn + j * 16 + lm;
#pragma unroll
      for (int r = 0; r < 4; ++r)
        C16[(size_t)(mrow + r) * ldc + col] = (_Float16)acc[i][j][r];
    }
  }
}

// ---------------------------------------------------------------------------
// Pipelined MFMA GEMM, 128x128 tile, BK=64, 4 waves 2x2.  A f16; W fp32
// (staging-converted).  fp32 C store, split-K via gridDim.z (+zstride).
// Used for out_proj: grid (8,16,OUT_SPLIT=4) = 512 blocks = 2/CU, nIter=8.
// ---------------------------------------------------------------------------
__global__ __launch_bounds__(256) void pgemm128f(
    const _Float16* __restrict__ A, int lda,
    const float* __restrict__ Wf, int ldw,
    float* __restrict__ C, int ldc, int K, size_t zstride)
{
  constexpr int PS = 1032;
  __shared__ _Float16 As[2][8 * PS];
  __shared__ _Float16 Bs[2][8 * PS];

  const int t  = threadIdx.x;
  const int m0 = blockIdx.y * 128, n0 = blockIdx.x * 128;
  const int kchunk = K / gridDim.z;
  const int kbeg = blockIdx.z * kchunk;
  const int nIter = kchunk / 64;

  const int kb = t & 7;
  const int r0 = t >> 3;
  const _Float16* gA = A + (size_t)(m0 + r0) * lda + kbeg + kb * 8;
  const float*    gB = Wf + (size_t)(n0 + r0) * ldw + kbeg + kb * 8;
  const size_t a32 = (size_t)32 * lda;
  const size_t b32 = (size_t)32 * ldw;
  const int soff = kb * PS + r0 * 8;

  {
    f16x8 ar[4], br[4];
#pragma unroll
    for (int j = 0; j < 4; ++j) {
      ar[j] = *(const f16x8*)(gA + j * a32);
      br[j] = cvt_f32x8(gB + j * b32);
    }
    gA += 64; gB += 64;
#pragma unroll
    for (int j = 0; j < 4; ++j) {
      *(f16x8*)&As[0][soff + j * 256] = ar[j];
      *(f16x8*)&Bs[0][soff + j * 256] = br[j];
    }
  }

  const int lane = t & 63, wvi = t >> 6;
  const int wm = (wvi >> 1) * 64, wn = (wvi & 1) * 64;
  const int lm = lane & 15, lk = lane >> 4;

  f32x4 acc[4][4] = {};

  for (int it = 0; it < nIter; ++it) {
    __syncthreads();
    const bool more = (it + 1 < nIter);
    f16x8 ar[4], br[4];
    if (more) {
#pragma unroll
      for (int j = 0; j < 4; ++j) {
        ar[j] = *(const f16x8*)(gA + j * a32);
        br[j] = cvt_f32x8(gB + j * b32);
      }
      gA += 64; gB += 64;
    }
    const int cb = it & 1;
#pragma unroll
    for (int s = 0; s < 2; ++s) {
      f16x8 av[4], bv[4];
#pragma unroll
      for (int i = 0; i < 4; ++i)
        av[i] = *(const f16x8*)&As[cb][(s * 4 + lk) * PS + (wm + i * 16 + lm) * 8];
#pragma unroll
      for (int j = 0; j < 4; ++j)
        bv[j] = *(const f16x8*)&Bs[cb][(s * 4 + lk) * PS + (wn + j * 16 + lm) * 8];
#pragma unroll
      for (int i = 0; i < 4; ++i)
#pragma unroll
        for (int j = 0; j < 4; ++j)
          acc[i][j] = __builtin_amdgcn_mfma_f32_16x16x32_f16(av[i], bv[j], acc[i][j], 0, 0, 0);
    }
    if (more) {
      const int nb = (it + 1) & 1;
#pragma unroll
      for (int j = 0; j < 4; ++j) {
        *(f16x8*)&As[nb][soff + j * 256] = ar[j];
        *(f16x8*)&Bs[nb][soff + j * 256] = br[j];
      }
    }
  }

  float* Cz = C + (size_t)blockIdx.z * zstride;
#pragma unroll
  for (int i = 0; i < 4; ++i) {
    const int mrow = m0 + wm + i * 16 + lk * 4;
#pragma unroll
    for (int j = 0; j < 4; ++j) {
      const int col = n0 + wn + j * 16 + lm;
#pragma unroll
      for (int r = 0; r < 4; ++r)
        Cz[(size_t)(mrow + r) * ldc + col] = acc[i][j][r];
    }
  }
}

// ---------------------------------------------------------------------------
// Pipelined MFMA GEMM, 64x128 tile, BK=64.  A f16; W fp32 (staging-converted,
// rows >= WROWS zero).  fp32 C store, split-K via gridDim.z (+zstride).
// Used for x_proj only (small-N, split-K=8 -> 256 blocks, nIter=4).
// ---------------------------------------------------------------------------
template<int WROWS>
__global__ __launch_bounds__(256) void pgemm64f(
    const _Float16* __restrict__ A, int lda,
    const float* __restrict__ Wf, int ldw,
    float* __restrict__ C, int ldc, int K, size_t zstride)
{
  constexpr int APS = 520;
  constexpr int BPS = 1032;
  __shared__ _Float16 As[2][8 * APS];
  __shared__ _Float16 Bs[2][8 * BPS];

  const int t  = threadIdx.x;
  const int m0 = blockIdx.y * 64, n0 = blockIdx.x * 128;
  const int kchunk = K / gridDim.z;
  const int kbeg = blockIdx.z * kchunk;
  const int nIter = kchunk / 64;

  const int kb = t & 7;
  const int r0 = t >> 3;
  const _Float16* gA = A + (size_t)(m0 + r0) * lda + kbeg + kb * 8;
  const float*    gB = Wf + (size_t)(n0 + r0) * ldw + kbeg + kb * 8;
  const size_t a32 = (size_t)32 * lda;
  const size_t b32 = (size_t)32 * ldw;
  const int aoff = kb * APS + r0 * 8;
  const int boff = kb * BPS + r0 * 8;

  {
    f16x8 a0 = *(const f16x8*)(gA);
    f16x8 a1 = *(const f16x8*)(gA + a32);
    f16x8 br[4];
#pragma unroll
    for (int j = 0; j < 4; ++j) {
      if (n0 + r0 + 32 * j < WROWS) br[j] = cvt_f32x8(gB + j * b32);
      else                          br[j] = (f16x8){};
    }
    gA += 64; gB += 64;
    *(f16x8*)&As[0][aoff]       = a0;
    *(f16x8*)&As[0][aoff + 256] = a1;
#pragma unroll
    for (int j = 0; j < 4; ++j)
      *(f16x8*)&Bs[0][boff + j * 256] = br[j];
  }

  const int lane = t & 63, wvi = t >> 6;
  const int wn = wvi * 32;
  const int lm = lane & 15, lk = lane >> 4;

  f32x4 acc[4][2] = {};

  for (int it = 0; it < nIter; ++it) {
    __syncthreads();
    const bool more = (it + 1 < nIter);
    f16x8 a0, a1, br[4];
    if (more) {
      a0 = *(const f16x8*)(gA);
      a1 = *(const f16x8*)(gA + a32);
#pragma unroll
      for (int j = 0; j < 4; ++j) {
        if (n0 + r0 + 32 * j < WROWS) br[j] = cvt_f32x8(gB + j * b32);
        else                          br[j] = (f16x8){};
      }
      gA += 64; gB += 64;
    }
    const int cb = it & 1;
#pragma unroll
    for (int s = 0; s < 2; ++s) {
      f16x8 av[4], bv[2];
#pragma unroll
      for (int i = 0; i < 4; ++i)
        av[i] = *(const f16x8*)&As[cb][(s * 4 + lk) * APS + (i * 16 + lm) * 8];
#pragma unroll
      for (int j = 0; j < 2; ++j)
        bv[j] = *(const f16x8*)&Bs[cb][(s * 4 + lk) * BPS + (wn + j * 16 + lm) * 8];
#pragma unroll
      for (int i = 0; i < 4; ++i)
#pragma unroll
        for (int j = 0; j < 2; ++j)
          acc[i][j] = __builtin_amdgcn_mfma_f32_16x16x32_f16(av[i], bv[j], acc[i][j], 0, 0, 0);
    }
    if (more) {
      const int nb = (it + 1) & 1;
      *(f16x8*)&As[nb][aoff]       = a0;
      *(f16x8*)&As[nb][aoff + 256] = a1;
#pragma unroll
      for (int j = 0; j < 4; ++j)
        *(f16x8*)&Bs[nb][boff + j * 256] = br[j];
    }
  }

  float* Cz = C + (size_t)blockIdx.z * zstride;
#pragma unroll
  for (int i = 0; i < 4; ++i) {
    const int mrow = m0 + i * 16 + lk * 4;
#pragma unroll
    for (int j = 0; j < 2; ++j) {
      const int col = n0 + wn + j * 16 + lm;
#pragma unroll
      for (int r = 0; r < 4; ++r)
        Cz[(size_t)(mrow + r) * ldc + col] = acc[i][j][r];
    }
  }
}

// ---------------------------------------------------------------------------
// Reduce out_proj split-K partials -> out fp32
// ---------------------------------------------------------------------------
__global__ __launch_bounds__(256) void reduce_out(
    const float* __restrict__ part, float* __restrict__ out)
{
  int i = blockIdx.x * 256 + threadIdx.x;          // float4 units, < 524288
  f32x4 s = ((const f32x4*)part)[i];
#pragma unroll
  for (int z = 1; z < OUT_SPLIT; ++z)
    s += ((const f32x4*)part)[(size_t)z * (MROWS * DMODEL / 4) + i];
  ((f32x4*)out)[i] = s;
}

// ---------------------------------------------------------------------------
// Causal depthwise conv (k=4) + bias + SiLU; xz is f16; writes u16.
// ---------------------------------------------------------------------------
__global__ __launch_bounds__(256) void conv_silu(
    const _Float16* __restrict__ xz16,
    const float* __restrict__ conv_w,
    const float* __restrict__ conv_b,
    _Float16* __restrict__ u16)
{
  const int idx = blockIdx.x * 256 + threadIdx.x;  // row*DINNER + d
  const int d   = idx & (DINNER - 1);
  const int row = idx >> 11;
  const int l   = row & (SEQLEN - 1);
  float s = conv_b[d];
#pragma unroll
  for (int k = 0; k < 4; ++k) {
    int lt = l + k - 3;
    if (lt >= 0)
      s = fmaf((float)xz16[(size_t)(row + k - 3) * (2 * DINNER) + d],
               conv_w[d * 4 + k], s);
  }
  float v = s / (1.f + __expf(-s));
  u16[idx] = (_Float16)v;
}

// ---------------------------------------------------------------------------
// sum the XP_SPLIT x_proj partials inline (same order as old reduce_xdbl)
// ---------------------------------------------------------------------------
__device__ __forceinline__ f32x4 red8(const float* __restrict__ part, size_t idx) {
  f32x4 s = *(const f32x4*)(part + idx);
#pragma unroll
  for (int z = 1; z < XP_SPLIT; ++z)
    s += *(const f32x4*)(part + (size_t)z * (MROWS * XPAD) + idx);
  return s;
}

// ---------------------------------------------------------------------------
// Serial-n selective scan with fused dt-projection; reads x_proj partials
// directly (inline split-K reduction).
// ---------------------------------------------------------------------------
__global__ __launch_bounds__(256) void scan_pe(
    const _Float16* __restrict__ u16,
    const float* __restrict__ part,        // [XP_SPLIT][MROWS][XPAD]
    const float* __restrict__ A_log,
    const float* __restrict__ dt_w,        // fp32 [DINNER][DTRANK]
    const float* __restrict__ dt_b,        // fp32 [DINNER]
    float* __restrict__ pbuf, float* __restrict__ ebuf,
    _Float16* __restrict__ delta16)
{
  const int t = threadIdx.x;
  const int d = blockIdx.x * 256 + t;
  const int b   = blockIdx.y >> 5;        // NSEG2 = 32
  const int seg = blockIdx.y & 31;
  const int row0 = b * SEQLEN + seg * SEGL2;

  f32x4 w[16];
#pragma unroll
  for (int q = 0; q < 16; ++q)
    w[q] = *(const f32x4*)&dt_w[(size_t)d * DTRANK + q * 4];
  const float b2 = 2.f * dt_b[d];

  float A_dn[DSTATE];
#pragma unroll
  for (int q = 0; q < 4; ++q) {
    f32x4 a4 = *(const f32x4*)&A_log[(size_t)d * DSTATE + q * 4];
#pragma unroll
    for (int e = 0; e < 4; ++e) A_dn[q * 4 + e] = -__expf(a4[e]);
  }

  __shared__ __align__(16) float xd[SEGL2 * 64];       // 8 KB, broadcast reads
  __shared__ __align__(16) float Bl[SEGL2 * DSTATE];   // 2 KB
  {
#pragma unroll
    for (int k = 0; k < 2; ++k) {
      int idx = t * 2 + k;
      int i = idx >> 4, c4 = (idx & 15) * 4;
      *(f32x4*)&xd[i * 64 + c4] = red8(part, (size_t)(row0 + i) * XPAD + c4);
    }
    if (t < 128) {
      int i = t >> 2, n4 = (t & 3) * 4;
      *(f32x4*)&Bl[i * DSTATE + n4] =
          red8(part, (size_t)(row0 + i) * XPAD + DTRANK + n4);
    }
  }
  __syncthreads();

  float E[DSTATE];
#pragma unroll
  for (int n = 0; n < DSTATE; ++n) E[n] = 0.f;
  float S = 0.f;

  for (int i = 0; i < SEGL2; ++i) {
    float a = b2;
#pragma unroll
    for (int q = 0; q < 16; ++q) {
      f32x4 x4 = *(const f32x4*)&xd[i * 64 + q * 4];
      a = fmaf(x4[0], w[q][0], a);
      a = fmaf(x4[1], w[q][1], a);
      a = fmaf(x4[2], w[q][2], a);
      a = fmaf(x4[3], w[q][3], a);
    }
    float dv = (a > 20.f) ? a : __logf(1.f + __expf(a));
    const size_t ro = (size_t)(row0 + i) * DINNER + d;
    delta16[ro] = (_Float16)dv;
    dv = (float)(_Float16)dv;              // match scan_y's f16-rounded delta
    float uv = (float)u16[ro];
    float du = dv * uv;
    S += dv;
#pragma unroll
    for (int n = 0; n < DSTATE; ++n) {
      float dA = __expf(dv * A_dn[n]);
      E[n] = fmaf(dA, E[n], du * Bl[i * DSTATE + n]);
    }
  }

  const size_t base = ((size_t)(b * NSEG2 + seg) * DSTATE) * DINNER + d;
#pragma unroll
  for (int n = 0; n < DSTATE; ++n) {
    pbuf[base + (size_t)n * DINNER] = __expf(S * A_dn[n]);
    ebuf[base + (size_t)n * DINNER] = E[n];
  }
}

__global__ __launch_bounds__(256) void scan_mid(
    const float* __restrict__ pbuf, const float* __restrict__ ebuf,
    float* __restrict__ cbuf)
{
  // idx over (b, n, d): 2*16*2048 = 65536 threads
  const int idx = blockIdx.x * 256 + threadIdx.x;
  const int d = idx & (DINNER - 1);
  const int n = (idx >> 11) & 15;
  const int b = idx >> 15;
  float s = 0.f;
  for (int seg = 0; seg < NSEG2; ++seg) {
    const size_t off = ((size_t)(b * NSEG2 + seg) * DSTATE + n) * DINNER + d;
    cbuf[off] = s;
    s = fmaf(pbuf[off], s, ebuf[off]);
  }
}

__global__ __launch_bounds__(256) void scan_y(
    const _Float16* __restrict__ delta16,
    const _Float16* __restrict__ u16,
    const _Float16* __restrict__ xz16,     // z = xz16[:, DINNER:]
    const float* __restrict__ part,        // x_proj partials
    const float* __restrict__ A_log,
    const float* __restrict__ Dp,
    const float* __restrict__ cbuf,
    _Float16* __restrict__ y16)
{
  const int t = threadIdx.x;
  const int d = blockIdx.x * 256 + t;
  const int b   = blockIdx.y >> 5;
  const int seg = blockIdx.y & 31;
  const int row0 = b * SEQLEN + seg * SEGL2;

  float A_dn[DSTATE];
#pragma unroll
  for (int q = 0; q < 4; ++q) {
    f32x4 a4 = *(const f32x4*)&A_log[(size_t)d * DSTATE + q * 4];
#pragma unroll
    for (int e = 0; e < 4; ++e) A_dn[q * 4 + e] = -__expf(a4[e]);
  }
  const float Dv = Dp[d];

  __shared__ __align__(16) float Bl[SEGL2 * DSTATE];   // 2 KB each
  __shared__ __align__(16) float Cl[SEGL2 * DSTATE];
  if (t < 128) {
    int i = t >> 2, n4 = (t & 3) * 4;
    *(f32x4*)&Bl[i * DSTATE + n4] =
        red8(part, (size_t)(row0 + i) * XPAD + DTRANK + n4);
  } else {
    int u = t - 128;
    int i = u >> 2, n4 = (u & 3) * 4;
    *(f32x4*)&Cl[i * DSTATE + n4] =
        red8(part, (size_t)(row0 + i) * XPAD + DTRANK + DSTATE + n4);
  }
  __syncthreads();

  float s[DSTATE];
  {
    const size_t base = ((size_t)(b * NSEG2 + seg) * DSTATE) * DINNER + d;
#pragma unroll
    for (int n = 0; n < DSTATE; ++n) s[n] = cbuf[base + (size_t)n * DINNER];
  }

  for (int i = 0; i < SEGL2; ++i) {
    const size_t ro = (size_t)(row0 + i) * DINNER + d;
    float dv = (float)delta16[ro];
    float uv = (float)u16[ro];
    float zv = (float)xz16[(size_t)(row0 + i) * (2 * DINNER) + DINNER + d];
    float du = dv * uv;
    float y = 0.f;
#pragma unroll
    for (int n = 0; n < DSTATE; ++n) {
      float dA = __expf(dv * A_dn[n]);
      s[n] = fmaf(dA, s[n], du * Bl[i * DSTATE + n]);
      y = fmaf(s[n], Cl[i * DSTATE + n], y);
    }
    y = fmaf(uv, Dv, y);
    y *= zv / (1.f + __expf(-zv));
    y16[ro] = (_Float16)y;
  }
}

// ---------------------------------------------------------------------------
extern "C" void kernel_launch(void* const* d_in, const int* in_sizes, int n_in,
                              void* d_out, int out_size, void* d_ws, size_t ws_size,
                              hipStream_t stream)
{
  const float* hidden     = (const float*)d_in[0];
  const float* in_proj_w  = (const float*)d_in[1];
  const float* conv_w     = (const float*)d_in[2];
  const float* conv_b     = (const float*)d_in[3];
  const float* x_proj_w   = (const float*)d_in[4];
  const float* dt_proj_w  = (const float*)d_in[5];
  const float* dt_proj_b  = (const float*)d_in[6];
  const float* A_log      = (const float*)d_in[7];
  const float* Dp         = (const float*)d_in[8];
  const float* out_proj_w = (const float*)d_in[9];
  float* out = (float*)d_out;

  char* p = (char*)d_ws;
  _Float16* xz16    = (_Float16*)p;  p += (size_t)MROWS * 2 * DINNER * 2;  // 16.8MB
  _Float16* u16     = (_Float16*)p;  p += (size_t)MROWS * DINNER * 2;      // 8.4MB
  _Float16* delta16 = (_Float16*)p;  p += (size_t)MROWS * DINNER * 2;      // 8.4MB
  _Float16* y16     = (_Float16*)p;  p += (size_t)MROWS * DINNER * 2;      // 8.4MB
  float*    xp_part = (float*)p;     p += (size_t)XP_SPLIT * MROWS * XPAD * 4; // 8.4MB
  float*    pbuf    = (float*)p;     p += (size_t)BATCH * NSEG2 * DSTATE * DINNER * 4; // 8.4MB
  float*    ebuf    = (float*)p;     p += (size_t)BATCH * NSEG2 * DSTATE * DINNER * 4; // 8.4MB
  float*    cbuf    = (float*)p;     p += (size_t)BATCH * NSEG2 * DSTATE * DINNER * 4; // 8.4MB
  // out_proj partials: 4 * 2048*1024*4 = 33.6MB, aliases xz16+u16+delta16
  // (all dead after scan_y; y16 lies beyond the aliased span).
  float*    out_part = (float*)xz16;

  // 1. in_proj: xz16 = f16(hidden @ in_proj_w^T)  [2048, 4096], K=1024
  pgemm128_f32<<<dim3(4096 / 128, MROWS / 128), 256, 0, stream>>>(
      hidden, DMODEL, in_proj_w, DMODEL, xz16, 4096, DMODEL);

  // 2. conv + SiLU -> u16
  conv_silu<<<(MROWS * DINNER) / 256, 256, 0, stream>>>(xz16, conv_w, conv_b, u16);

  // 3. x_proj: partials[z] = u @ x_proj_w^T chunk  [2048,128], split-K=8
  pgemm64f<96><<<dim3(1, MROWS / 64, XP_SPLIT), 256, 0, stream>>>(
      u16, DINNER, x_proj_w, DINNER, xp_part, XPAD, DINNER,
      (size_t)MROWS * XPAD);

  // 4+5. serial-n scan, fused dt-projection, inline split-K reduction
  scan_pe<<<dim3(DINNER / 256, BATCH * NSEG2), 256, 0, stream>>>(
      u16, xp_part, A_log, dt_proj_w, dt_proj_b, pbuf, ebuf, delta16);
  scan_mid<<<(BATCH * DSTATE * DINNER) / 256, 256, 0, stream>>>(pbuf, ebuf, cbuf);
  scan_y<<<dim3(DINNER / 256, BATCH * NSEG2), 256, 0, stream>>>(
      delta16, u16, xz16, xp_part, A_log, Dp, cbuf, y16);

  // 6. out_proj: partials[z] = y @ out_proj_w^T chunk, split-K=4,
  //    128x128 tile (512 blocks = 2/CU, nIter=8 -- fixes R10's 93us
  //    latency-serialized 64-row un-split config)
  pgemm128f<<<dim3(DMODEL / 128, MROWS / 128, OUT_SPLIT), 256, 0, stream>>>(
      y16, DINNER, out_proj_w, DINNER, out_part, DMODEL, DINNER,
      (size_t)MROWS * DMODEL);

  // 6b. reduce -> out
  reduce_out<<<(MROWS * DMODEL / 4) / 256, 256, 0, stream>>>(out_part, out);
}